// Round 11
// baseline (155.956 us; speedup 1.0000x reference)
//
#include <hip/hip_runtime.h>
#include <hip/hip_bf16.h>

typedef __attribute__((ext_vector_type(8))) short bf16x8;
typedef __attribute__((ext_vector_type(4))) float f32x4;

#define S_LEN 2048
#define EMB   1024
#define NH    16
#define HD    64

// XOR-swizzled LDS addressing: 64-col bf16 tiles, 8-elem (16 B) chunks.
// elem(row, chunk) = row*64 + ((chunk ^ (row&7))*8). Verified: 0 conflicts.
__device__ inline int swz(int row, int chunk) {
  return row * 64 + ((chunk ^ (row & 7)) << 3);
}

// 128-col variant (16 chunks/row) for the V tile [dim][key] at KVBLK=128.
__device__ inline int swz128(int row, int chunk) {
  return row * 128 + ((chunk ^ (row & 15)) << 3);
}

// K-row permutation: storing K row s at position [s5,s2,s4,s3,s1,s0] makes
// the exp(S^T) C-layout registers exactly the mfma_16x16x32 A-fragment for
// natural-order V; PV uses K=32 MFMA with b128 V reads, no fixup.
// At KVBLK=128 it applies within each 64-key half (bit 6 preserved).
__device__ inline int kperm(int s) {
  return (s & 0x23) | ((s & 0x04) << 2) | ((s & 0x18) >> 1);
}

// Convert 8 contiguous f32 -> 8 bf16 (RNE) packed in a uint4, optional scale.
__device__ inline uint4 cvt8(const float* __restrict__ src, float scale) {
  float4 f0 = ((const float4*)src)[0];
  float4 f1 = ((const float4*)src)[1];
  __hip_bfloat16 t[8];
  t[0] = __float2bfloat16(f0.x * scale);
  t[1] = __float2bfloat16(f0.y * scale);
  t[2] = __float2bfloat16(f0.z * scale);
  t[3] = __float2bfloat16(f0.w * scale);
  t[4] = __float2bfloat16(f1.x * scale);
  t[5] = __float2bfloat16(f1.y * scale);
  t[6] = __float2bfloat16(f1.z * scale);
  t[7] = __float2bfloat16(f1.w * scale);
  return *(uint4*)t;
}

// ---------------------------------------------------------------------------
// prep: K f32->bf16 (Kb) + V transpose (Vt). W convert lives in the attn
// dispatch as backfill blocks (R19: absorbed for free — attn time unchanged
// while prep shrank).
//   Kb[((b*NH+h)*S + s)*64 + d]  (head-major, rows = keys)
//   Vt[((b*NH+h)*64 + d)*S + s]  (transposed, rows = dims)
// ---------------------------------------------------------------------------
__global__ __launch_bounds__(256)
void prep(const float* __restrict__ K, const float* __restrict__ V,
          __hip_bfloat16* __restrict__ Kb, __hip_bfloat16* __restrict__ Vt) {
  __shared__ float vt[64 * 65];
  const int tid = threadIdx.x;
  const int st = blockIdx.x, h = blockIdx.y, b = blockIdx.z;
  const size_t srcbase = ((size_t)(b * S_LEN + st * 64)) * EMB + h * HD;
  const size_t kvb = ((size_t)(b * NH + h) * S_LEN + st * 64) * HD;
  const size_t vtb = ((size_t)(b * NH + h) * HD) * S_LEN + st * 64;

  for (int c = tid; c < 512; c += 256) {
    const int r = c >> 3, c8 = (c & 7) * 8;
    *(uint4*)(Kb + kvb + r * HD + c8) = cvt8(K + srcbase + (size_t)r * EMB + c8, 1.0f);
    const float* vsrc = V + srcbase + (size_t)r * EMB + c8;
    float4 a = ((const float4*)vsrc)[0];
    float4 d4 = ((const float4*)vsrc)[1];
    float tv[8] = {a.x, a.y, a.z, a.w, d4.x, d4.y, d4.z, d4.w};
    #pragma unroll
    for (int j = 0; j < 8; ++j) vt[r * 65 + c8 + j] = tv[j];
  }
  __syncthreads();
  for (int c = tid; c < 512; c += 256) {
    const int d = c >> 3, s8 = (c & 7) * 8;
    __hip_bfloat16 t[8];
    #pragma unroll
    for (int j = 0; j < 8; ++j)
      t[j] = __float2bfloat16(vt[(s8 + j) * 65 + d]);
    *(uint4*)(Vt + vtb + (size_t)d * S_LEN + s8) = *(uint4*)t;
  }
}

// ---------------------------------------------------------------------------
// Flash attention — R13 core (measured optimum across 6 schedule variants:
// 46.5 us) + R20 XCD-aware block swizzle (T1). Motivation: FETCH 75.8 MB vs
// ~36 MB ideal — the 16 qt-blocks sharing one (h,b)'s Kb/Vt slice round-robin
// across the 8 XCD L2s, so every XCD refetches every slice. Bijective remap
// vid = (flat&7)*64 + flat>>3 (512 = 8x64) gives each XCD whole (h,b)
// groups -> shared slices fetched ~once per XCD. Pure index remap: layout,
// sync, arithmetic all unchanged -> bit-identical output.
// Core: KVBLK=128, 512 thr = 8 waves x 16 queries, 2 blocks/CU. 16 QK MFMAs
// back-to-back; exp/pack half-A; PV t=0,1 ∥ exp/pack half-B; PV t=2,3;
// setprio around MFMA clusters; raw v_exp_f32; elementwise bf16 cvt
// (compiler pairs to v_cvt_pk; hand-asm pack was UB — R11); lsum on the
// MFMA pipe (ones-fragment). Double-buffered, 1 barrier/iter, 80 KB LDS.
// blockIdx.z==2 slice: W f32->bf16 backfill (256 blocks, proj dependency).
// ---------------------------------------------------------------------------
__global__ __launch_bounds__(512, 4)
void attn_fwd(const float* __restrict__ Q,
              const __hip_bfloat16* __restrict__ Kb,
              const __hip_bfloat16* __restrict__ Vt,
              const float* __restrict__ W,
              __hip_bfloat16* __restrict__ Wb,
              __hip_bfloat16* __restrict__ O)
{
  if (blockIdx.z == 2) {   // W convert backfill: 256 blocks x 512 thr x 8 elems
    const int widx = blockIdx.y * 16 + blockIdx.x;
    const int i = (widx * 512 + (int)threadIdx.x) * 8;
    *(uint4*)(Wb + i) = cvt8(W + i, 1.0f);
    return;
  }

  __shared__ __align__(16) __hip_bfloat16 qs[128 * 64];      // 16 KB
  __shared__ __align__(16) __hip_bfloat16 ks[2][128 * 64];   // 32 KB [key][dim]
  __shared__ __align__(16) __hip_bfloat16 vs[2][64 * 128];   // 32 KB [dim][key]

  // XCD-aware swizzle: dispatch order flat -> virtual tile id. 512 % 8 == 0
  // so the remap is bijective; XCD x gets vid in [x*64, x*64+64) = 4 whole
  // (h,b) groups of 16 qt-tiles each.
  const int flat = (int)blockIdx.x + 16 * (int)blockIdx.y + 256 * (int)blockIdx.z;
  const int vid  = (flat & 7) * 64 + (flat >> 3);
  const int qt   = vid & 15;
  const int h    = (vid >> 4) & 15;
  const int b    = vid >> 8;
  const int tid  = threadIdx.x;
  const int wave = tid >> 6;
  const int lane = tid & 63;
  const int ln   = lane & 15;
  const int qd   = lane >> 4;

  const size_t baseQ = ((size_t)(b * S_LEN + qt * 128)) * EMB + h * HD;
  const size_t kvb   = ((size_t)(b * NH + h) * S_LEN) * HD;
  const size_t vtb   = ((size_t)(b * NH + h) * HD) * S_LEN;

  // staging maps (loop-invariant write addrs)
  const int r0 = tid >> 3, cc = tid & 7;
  const int kpos0 = swz(kperm(r0), cc);
  const int kpos1 = kpos0 + 64 * 64;           // kperm within half, bit6 kept
  const int vr0 = tid >> 4, vch = tid & 15;
  const int vpos0 = swz128(vr0, vch);
  const int vpos1 = vpos0 + 32 * 128;          // (vr0+32)&15 == vr0&15

  // prefetch tile 0
  uint4 kreg0 = *(const uint4*)(Kb + kvb + (size_t)(r0)       * HD + cc * 8);
  uint4 kreg1 = *(const uint4*)(Kb + kvb + (size_t)(64 + r0)  * HD + cc * 8);
  uint4 vreg0 = *(const uint4*)(Vt + vtb + (size_t)vr0        * S_LEN + vch * 8);
  uint4 vreg1 = *(const uint4*)(Vt + vtb + (size_t)(vr0 + 32) * S_LEN + vch * 8);

  // stage Q (f32 -> bf16, scale = 0.125*log2(e); P = exp2(S'))
  const float qscale = 0.125f * 1.44269504088896f;
  #pragma unroll
  for (int i = 0; i < 2; ++i) {
    const int c = tid + 512 * i, row = c >> 3, ch = c & 7;
    *(uint4*)&qs[swz(row, ch)] = cvt8(Q + baseQ + (size_t)row * EMB + ch * 8, qscale);
  }
  // write tile 0, prefetch tile 1
  *(uint4*)&ks[0][kpos0] = kreg0;
  *(uint4*)&ks[0][kpos1] = kreg1;
  *(uint4*)&vs[0][vpos0] = vreg0;
  *(uint4*)&vs[0][vpos1] = vreg1;
  kreg0 = *(const uint4*)(Kb + kvb + (size_t)(128 + r0)      * HD + cc * 8);
  kreg1 = *(const uint4*)(Kb + kvb + (size_t)(192 + r0)      * HD + cc * 8);
  vreg0 = *(const uint4*)(Vt + vtb + (size_t)vr0        * S_LEN + 128 + vch * 8);
  vreg1 = *(const uint4*)(Vt + vtb + (size_t)(vr0 + 32) * S_LEN + 128 + vch * 8);
  __syncthreads();   // qs + buf0 ready

  // Q B-fragments (n = query = ln, k = qd*8+j), loop-invariant
  bf16x8 aq[2];
  #pragma unroll
  for (int kh = 0; kh < 2; ++kh)
    aq[kh] = *(const bf16x8*)&qs[swz(wave * 16 + ln, kh * 4 + qd)];

  // ones B-fragment for lsum-on-MFMA: D[q][*] = sum_k P[q][k]
  bf16x8 ones;
  #pragma unroll
  for (int j = 0; j < 8; ++j) ones[j] = (short)0x3F80;   // bf16 1.0

  f32x4 oacc[4] = {};   // [dn]; C: col=dim=ln, row=query=qd*4+r
  f32x4 lacc = {};      // row sums; C: row=query=qd*4+r (col replicated)

  for (int kt = 0; kt < S_LEN / 128; ++kt) {
    const int cur = kt & 1;
    if (kt + 1 < S_LEN / 128) {     // regs loaded one full iter ago: no stall
      *(uint4*)&ks[1 - cur][kpos0] = kreg0;
      *(uint4*)&ks[1 - cur][kpos1] = kreg1;
      *(uint4*)&vs[1 - cur][vpos0] = vreg0;
      *(uint4*)&vs[1 - cur][vpos1] = vreg1;
      if (kt + 2 < S_LEN / 128) {
        const int kb2 = (kt + 2) * 128;
        kreg0 = *(const uint4*)(Kb + kvb + (size_t)(kb2 + r0)       * HD + cc * 8);
        kreg1 = *(const uint4*)(Kb + kvb + (size_t)(kb2 + 64 + r0)  * HD + cc * 8);
        vreg0 = *(const uint4*)(Vt + vtb + (size_t)vr0        * S_LEN + kb2 + vch * 8);
        vreg1 = *(const uint4*)(Vt + vtb + (size_t)(vr0 + 32) * S_LEN + kb2 + vch * 8);
      }
    }

    // ---- S^T = K Q^T, both 64-key halves back-to-back: 16 independent
    // MFMAs fill the matrix pipe while the trans pipe is still free.
    f32x4 sfA[4], sfB[4];
    __builtin_amdgcn_s_setprio(1);
    #pragma unroll
    for (int k16 = 0; k16 < 4; ++k16) {
      const int krow = k16 * 16 + ln;
      bf16x8 ak0 = *(const bf16x8*)&ks[cur][swz(krow, qd)];
      bf16x8 ak1 = *(const bf16x8*)&ks[cur][swz(krow, 4 + qd)];
      f32x4 acc = {};
      acc = __builtin_amdgcn_mfma_f32_16x16x32_bf16(ak0, aq[0], acc, 0, 0, 0);
      sfA[k16] = __builtin_amdgcn_mfma_f32_16x16x32_bf16(ak1, aq[1], acc, 0, 0, 0);
    }
    #pragma unroll
    for (int k16 = 0; k16 < 4; ++k16) {
      const int krow = (4 + k16) * 16 + ln;
      bf16x8 ak0 = *(const bf16x8*)&ks[cur][swz(krow, qd)];
      bf16x8 ak1 = *(const bf16x8*)&ks[cur][swz(krow, 4 + qd)];
      f32x4 acc = {};
      acc = __builtin_amdgcn_mfma_f32_16x16x32_bf16(ak0, aq[0], acc, 0, 0, 0);
      sfB[k16] = __builtin_amdgcn_mfma_f32_16x16x32_bf16(ak1, aq[1], acc, 0, 0, 0);
    }
    __builtin_amdgcn_s_setprio(0);

    // ---- exp/pack half A -> apA[0..1] (trans pipe; overlaps QK-B tail) ----
    bf16x8 apA[2];
    #pragma unroll
    for (int t2 = 0; t2 < 2; ++t2)
      #pragma unroll
      for (int j = 0; j < 8; ++j) {
        const float p = __builtin_amdgcn_exp2f(sfA[t2 * 2 + (j >> 2)][j & 3]);
        __hip_bfloat16 hb = __float2bfloat16(p);
        apA[t2][j] = *(short*)&hb;
      }

    // ---- PV + lsum for t=0,1 (10 MFMA) — overlaps exp/pack of half B ----
    __builtin_amdgcn_s_setprio(1);
    #pragma unroll
    for (int t = 0; t < 2; ++t) {
      lacc = __builtin_amdgcn_mfma_f32_16x16x32_bf16(apA[t], ones, lacc, 0, 0, 0);
      #pragma unroll
      for (int dn = 0; dn < 4; ++dn) {
        bf16x8 bv = *(const bf16x8*)&vs[cur][swz128(dn * 16 + ln, t * 4 + qd)];
        oacc[dn] = __builtin_amdgcn_mfma_f32_16x16x32_bf16(apA[t], bv, oacc[dn], 0, 0, 0);
      }
    }
    __builtin_amdgcn_s_setprio(0);

    // ---- exp/pack half B -> apB[0..1] ----
    bf16x8 apB[2];
    #pragma unroll
    for (int t2 = 0; t2 < 2; ++t2)
      #pragma unroll
      for (int j = 0; j < 8; ++j) {
        const float p = __builtin_amdgcn_exp2f(sfB[t2 * 2 + (j >> 2)][j & 3]);
        __hip_bfloat16 hb = __float2bfloat16(p);
        apB[t2][j] = *(short*)&hb;
      }

    // ---- PV + lsum for t=2,3 ----
    __builtin_amdgcn_s_setprio(1);
    #pragma unroll
    for (int t = 0; t < 2; ++t) {
      lacc = __builtin_amdgcn_mfma_f32_16x16x32_bf16(apB[t], ones, lacc, 0, 0, 0);
      #pragma unroll
      for (int dn = 0; dn < 4; ++dn) {
        bf16x8 bv = *(const bf16x8*)&vs[cur][swz128(dn * 16 + ln, (2 + t) * 4 + qd)];
        oacc[dn] = __builtin_amdgcn_mfma_f32_16x16x32_bf16(apB[t], bv, oacc[dn], 0, 0, 0);
      }
    }
    __builtin_amdgcn_s_setprio(0);

    __syncthreads();   // single barrier per iteration
  }

  // ---- epilogue: lacc[r] is already this lane's row sums -> normalize ----
  #pragma unroll
  for (int r = 0; r < 4; ++r) {
    const float inv = 1.f / lacc[r];
    const int row = wave * 16 + qd * 4 + r;
    #pragma unroll
    for (int dn = 0; dn < 4; ++dn)
      O[baseQ + (size_t)row * EMB + dn * 16 + ln] =
          __float2bfloat16(oacc[dn][r] * inv);
  }
}

// ---------------------------------------------------------------------------
// Projection (R11/R13-verified) + R20 XCD swizzle: blocks sharing an n-panel
// of W (same n0, 32 m-tiles) now land on one XCD -> W panel fetched ~once
// per XCD instead of 8x. 128x64 tile, 512 blocks = 2 blocks/CU, 4 waves 2x2,
// 16 MFMA per 12 LDS reads per BK=64 iter, double-buffered, 1 barrier/iter,
// XOR swizzle, LDS 48 KB.
// ---------------------------------------------------------------------------
__global__ __launch_bounds__(256, 2)
void proj_prelu(const __hip_bfloat16* __restrict__ X,
                const __hip_bfloat16* __restrict__ Wb,
                const float* __restrict__ Bv,
                const float* __restrict__ Pa,
                float* __restrict__ Out)
{
  __shared__ __align__(16) __hip_bfloat16 xs[2][128 * 64];   // 32 KB
  __shared__ __align__(16) __hip_bfloat16 wsm[2][64 * 64];   // 16 KB

  // XCD-aware swizzle (bijective, 512 = 8 x 64): XCD x gets vid in
  // [x*64, x*64+64) = 2 whole n-groups of 32 m-tiles.
  const int flat = (int)blockIdx.x + 32 * (int)blockIdx.y;
  const int vid  = (flat & 7) * 64 + (flat >> 3);
  const int m0   = (vid & 31) * 128;
  const int n0   = (vid >> 5) * 64;
  const int tid  = threadIdx.x;
  const int wave = tid >> 6;
  const int wm   = wave >> 1;      // 0..1 : 64-row half
  const int wn   = wave & 1;       // 0..1 : 32-col half
  const int lane = tid & 63;
  const int ln   = lane & 15;
  const int qd   = lane >> 4;
  const int r0 = tid >> 3, cc = tid & 7;

  f32x4 acc[8] = {};   // [mf*2+nf]

  uint4 xg0, xg1, xg2, xg3, wg0, wg1;
  #define LOADK(ko)                                                           \
    xg0 = *(const uint4*)(X  + (size_t)(m0 + r0     ) * EMB + (ko) + cc * 8); \
    xg1 = *(const uint4*)(X  + (size_t)(m0 + r0 + 32) * EMB + (ko) + cc * 8); \
    xg2 = *(const uint4*)(X  + (size_t)(m0 + r0 + 64) * EMB + (ko) + cc * 8); \
    xg3 = *(const uint4*)(X  + (size_t)(m0 + r0 + 96) * EMB + (ko) + cc * 8); \
    wg0 = *(const uint4*)(Wb + (size_t)(n0 + r0     ) * EMB + (ko) + cc * 8); \
    wg1 = *(const uint4*)(Wb + (size_t)(n0 + r0 + 32) * EMB + (ko) + cc * 8)
  #define STORELDS(buf)                                                       \
    *(uint4*)&xs [buf][swz(r0,      cc)] = xg0;                               \
    *(uint4*)&xs [buf][swz(r0 + 32, cc)] = xg1;                               \
    *(uint4*)&xs [buf][swz(r0 + 64, cc)] = xg2;                               \
    *(uint4*)&xs [buf][swz(r0 + 96, cc)] = xg3;                               \
    *(uint4*)&wsm[buf][swz(r0,      cc)] = wg0;                               \
    *(uint4*)&wsm[buf][swz(r0 + 32, cc)] = wg1

  LOADK(0);
  STORELDS(0);
  LOADK(64);
  __syncthreads();

  for (int kt = 0; kt < EMB / 64; ++kt) {
    const int cur = kt & 1;
    if (kt + 1 < EMB / 64) {
      STORELDS(1 - cur);
      if (kt + 2 < EMB / 64) {
        LOADK((kt + 2) * 64);
      }
    }

    #pragma unroll
    for (int ks2 = 0; ks2 < 2; ++ks2) {   // two K=32 steps
      bf16x8 ax0 = *(const bf16x8*)&xs[cur][swz(wm * 64 +  0 + ln, ks2 * 4 + qd)];
      bf16x8 ax1 = *(const bf16x8*)&xs[cur][swz(wm * 64 + 16 + ln, ks2 * 4 + qd)];
      bf16x8 ax2 = *(const bf16x8*)&xs[cur][swz(wm * 64 + 32 + ln, ks2 * 4 + qd)];
      bf16x8 ax3 = *(const bf16x8*)&xs[cur][swz(wm * 64 + 48 + ln, ks2 * 4 + qd)];
      bf16x8 bw0 = *(const bf16x8*)&wsm[cur][swz(wn * 32 +  0 + ln, ks2 * 4 + qd)];
      bf16x8 bw1 = *(const bf16x8*)&wsm[cur][swz(wn * 32 + 16 + ln, ks2 * 4 + qd)];
      acc[0] = __builtin_amdgcn_mfma_f32_16x16x32_bf16(ax0, bw0, acc[0], 0, 0, 0);
      acc[1] = __builtin_amdgcn_mfma_f32_16x16x32_bf16(ax0, bw1, acc[1], 0, 0, 0);
      acc[2] = __builtin_amdgcn_mfma_f32_16x16x32_bf16(ax1, bw0, acc[2], 0, 0, 0);
      acc[3] = __builtin_amdgcn_mfma_f32_16x16x32_bf16(ax1, bw1, acc[3], 0, 0, 0);
      acc[4] = __builtin_amdgcn_mfma_f32_16x16x32_bf16(ax2, bw0, acc[4], 0, 0, 0);
      acc[5] = __builtin_amdgcn_mfma_f32_16x16x32_bf16(ax2, bw1, acc[5], 0, 0, 0);
      acc[6] = __builtin_amdgcn_mfma_f32_16x16x32_bf16(ax3, bw0, acc[6], 0, 0, 0);
      acc[7] = __builtin_amdgcn_mfma_f32_16x16x32_bf16(ax3, bw1, acc[7], 0, 0, 0);
    }
    __syncthreads();
  }

  const float a = Pa[0];
  #pragma unroll
  for (int mf = 0; mf < 4; ++mf) {
    #pragma unroll
    for (int nf = 0; nf < 2; ++nf) {
      const float bn = Bv[n0 + wn * 32 + nf * 16 + ln];
      #pragma unroll
      for (int r = 0; r < 4; ++r) {
        float y = acc[mf * 2 + nf][r] + bn;
        y = (y >= 0.f) ? y : a * y;
        Out[(size_t)(m0 + wm * 64 + mf * 16 + qd * 4 + r) * EMB +
            n0 + wn * 32 + nf * 16 + ln] = y;
      }
    }
  }
  #undef LOADK
  #undef STORELDS
}

extern "C" void kernel_launch(void* const* d_in, const int* in_sizes, int n_in,
                              void* d_out, int out_size, void* d_ws, size_t ws_size,
                              hipStream_t stream) {
  const float* Q  = (const float*)d_in[0];
  const float* K  = (const float*)d_in[1];
  const float* V  = (const float*)d_in[2];
  const float* W  = (const float*)d_in[3];
  const float* Bb = (const float*)d_in[4];
  const float* Pa = (const float*)d_in[5];
  float* Out = (float*)d_out;

  // workspace (bytes): X 0..8M, Kb 8..16M, Vt 16..24M, Wb 24..26M
  char* ws = (char*)d_ws;
  __hip_bfloat16* Xws = (__hip_bfloat16*)(ws);
  __hip_bfloat16* Kb  = (__hip_bfloat16*)(ws + (8u  << 20));
  __hip_bfloat16* Vt  = (__hip_bfloat16*)(ws + (16u << 20));
  __hip_bfloat16* Wb  = (__hip_bfloat16*)(ws + (24u << 20));

  prep      <<<dim3(S_LEN / 64, NH, 2), 256, 0, stream>>>(K, V, Kb, Vt);
  attn_fwd  <<<dim3(S_LEN / 128, NH, 3), 512, 0, stream>>>(Q, Kb, Vt, W, Wb, Xws);
  proj_prelu<<<dim3(2 * S_LEN / 128, EMB / 64), 256, 0, stream>>>(Xws, Wb, Bb, Pa, Out);
}

// Round 12
// 152.935 us; speedup vs baseline: 1.0198x; 1.0198x over previous
//
#include <hip/hip_runtime.h>
#include <hip/hip_bf16.h>

typedef __attribute__((ext_vector_type(8))) short bf16x8;
typedef __attribute__((ext_vector_type(4))) float f32x4;

#define S_LEN 2048
#define EMB   1024
#define NH    16
#define HD    64

// XOR-swizzled LDS addressing: 64-col bf16 tiles, 8-elem (16 B) chunks.
// elem(row, chunk) = row*64 + ((chunk ^ (row&7))*8). Verified: 0 conflicts.
__device__ inline int swz(int row, int chunk) {
  return row * 64 + ((chunk ^ (row & 7)) << 3);
}

// 128-col variant (16 chunks/row) for the V tile [dim][key] at KVBLK=128.
__device__ inline int swz128(int row, int chunk) {
  return row * 128 + ((chunk ^ (row & 15)) << 3);
}

// K-row permutation: storing K row s at position [s5,s2,s4,s3,s1,s0] makes
// the exp(S^T) C-layout registers exactly the mfma_16x16x32 A-fragment for
// natural-order V; PV uses K=32 MFMA with b128 V reads, no fixup.
// At KVBLK=128 it applies within each 64-key half (bit 6 preserved).
__device__ inline int kperm(int s) {
  return (s & 0x23) | ((s & 0x04) << 2) | ((s & 0x18) >> 1);
}

// Convert 8 contiguous f32 -> 8 bf16 (RNE) packed in a uint4, optional scale.
__device__ inline uint4 cvt8(const float* __restrict__ src, float scale) {
  float4 f0 = ((const float4*)src)[0];
  float4 f1 = ((const float4*)src)[1];
  __hip_bfloat16 t[8];
  t[0] = __float2bfloat16(f0.x * scale);
  t[1] = __float2bfloat16(f0.y * scale);
  t[2] = __float2bfloat16(f0.z * scale);
  t[3] = __float2bfloat16(f0.w * scale);
  t[4] = __float2bfloat16(f1.x * scale);
  t[5] = __float2bfloat16(f1.y * scale);
  t[6] = __float2bfloat16(f1.z * scale);
  t[7] = __float2bfloat16(f1.w * scale);
  return *(uint4*)t;
}

// ---------------------------------------------------------------------------
// prep: K f32->bf16 (Kb) + V transpose (Vt). W convert lives in the attn
// dispatch as backfill blocks (R19: absorbed for free).
//   Kb[((b*NH+h)*S + s)*64 + d]  (head-major, rows = keys)
//   Vt[((b*NH+h)*64 + d)*S + s]  (transposed, rows = dims)
// ---------------------------------------------------------------------------
__global__ __launch_bounds__(256)
void prep(const float* __restrict__ K, const float* __restrict__ V,
          __hip_bfloat16* __restrict__ Kb, __hip_bfloat16* __restrict__ Vt) {
  __shared__ float vt[64 * 65];
  const int tid = threadIdx.x;
  const int st = blockIdx.x, h = blockIdx.y, b = blockIdx.z;
  const size_t srcbase = ((size_t)(b * S_LEN + st * 64)) * EMB + h * HD;
  const size_t kvb = ((size_t)(b * NH + h) * S_LEN + st * 64) * HD;
  const size_t vtb = ((size_t)(b * NH + h) * HD) * S_LEN + st * 64;

  for (int c = tid; c < 512; c += 256) {
    const int r = c >> 3, c8 = (c & 7) * 8;
    *(uint4*)(Kb + kvb + r * HD + c8) = cvt8(K + srcbase + (size_t)r * EMB + c8, 1.0f);
    const float* vsrc = V + srcbase + (size_t)r * EMB + c8;
    float4 a = ((const float4*)vsrc)[0];
    float4 d4 = ((const float4*)vsrc)[1];
    float tv[8] = {a.x, a.y, a.z, a.w, d4.x, d4.y, d4.z, d4.w};
    #pragma unroll
    for (int j = 0; j < 8; ++j) vt[r * 65 + c8 + j] = tv[j];
  }
  __syncthreads();
  for (int c = tid; c < 512; c += 256) {
    const int d = c >> 3, s8 = (c & 7) * 8;
    __hip_bfloat16 t[8];
    #pragma unroll
    for (int j = 0; j < 8; ++j)
      t[j] = __float2bfloat16(vt[(s8 + j) * 65 + d]);
    *(uint4*)(Vt + vtb + (size_t)d * S_LEN + s8) = *(uint4*)t;
  }
}

// ---------------------------------------------------------------------------
// Flash attention — FINAL: R13 core verbatim (measured optimum, 46.5 us).
// R20's XCD swizzle is REVERTED: it cut FETCH 75.8->18.5 MB yet cost +2.8 us
// — definitive proof the kernel is dependency-latency-bound, not memory-
// bound at any cache level. Natural dispatch order restored.
// Core: KVBLK=128, 512 thr = 8 waves x 16 queries, 2 blocks/CU. 16 QK MFMAs
// back-to-back; exp/pack half-A; PV t=0,1 ∥ exp/pack half-B; PV t=2,3;
// setprio around MFMA clusters; raw v_exp_f32 (OCML exp2f call was the
// original VALU bloat, R12: -17 us); elementwise bf16 cvt (compiler pairs to
// v_cvt_pk; hand-asm pack was UB — R11); lsum on the MFMA pipe via
// ones-fragment (kills epilogue shuffle-reduce). Double-buffered register
// prefetch, 1 barrier/iter, 80 KB LDS.
// blockIdx.z==2 slice: W f32->bf16 backfill (256 blocks; fills CU gaps free).
// ---------------------------------------------------------------------------
__global__ __launch_bounds__(512, 4)
void attn_fwd(const float* __restrict__ Q,
              const __hip_bfloat16* __restrict__ Kb,
              const __hip_bfloat16* __restrict__ Vt,
              const float* __restrict__ W,
              __hip_bfloat16* __restrict__ Wb,
              __hip_bfloat16* __restrict__ O)
{
  if (blockIdx.z == 2) {   // W convert backfill: 256 blocks x 512 thr x 8 elems
    const int widx = blockIdx.y * 16 + blockIdx.x;
    const int i = (widx * 512 + (int)threadIdx.x) * 8;
    *(uint4*)(Wb + i) = cvt8(W + i, 1.0f);
    return;
  }

  __shared__ __align__(16) __hip_bfloat16 qs[128 * 64];      // 16 KB
  __shared__ __align__(16) __hip_bfloat16 ks[2][128 * 64];   // 32 KB [key][dim]
  __shared__ __align__(16) __hip_bfloat16 vs[2][64 * 128];   // 32 KB [dim][key]

  const int qt   = blockIdx.x;
  const int h    = blockIdx.y;
  const int b    = blockIdx.z;
  const int tid  = threadIdx.x;
  const int wave = tid >> 6;
  const int lane = tid & 63;
  const int ln   = lane & 15;
  const int qd   = lane >> 4;

  const size_t baseQ = ((size_t)(b * S_LEN + qt * 128)) * EMB + h * HD;
  const size_t kvb   = ((size_t)(b * NH + h) * S_LEN) * HD;
  const size_t vtb   = ((size_t)(b * NH + h) * HD) * S_LEN;

  // staging maps (loop-invariant write addrs)
  const int r0 = tid >> 3, cc = tid & 7;
  const int kpos0 = swz(kperm(r0), cc);
  const int kpos1 = kpos0 + 64 * 64;           // kperm within half, bit6 kept
  const int vr0 = tid >> 4, vch = tid & 15;
  const int vpos0 = swz128(vr0, vch);
  const int vpos1 = vpos0 + 32 * 128;          // (vr0+32)&15 == vr0&15

  // prefetch tile 0
  uint4 kreg0 = *(const uint4*)(Kb + kvb + (size_t)(r0)       * HD + cc * 8);
  uint4 kreg1 = *(const uint4*)(Kb + kvb + (size_t)(64 + r0)  * HD + cc * 8);
  uint4 vreg0 = *(const uint4*)(Vt + vtb + (size_t)vr0        * S_LEN + vch * 8);
  uint4 vreg1 = *(const uint4*)(Vt + vtb + (size_t)(vr0 + 32) * S_LEN + vch * 8);

  // stage Q (f32 -> bf16, scale = 0.125*log2(e); P = exp2(S'))
  const float qscale = 0.125f * 1.44269504088896f;
  #pragma unroll
  for (int i = 0; i < 2; ++i) {
    const int c = tid + 512 * i, row = c >> 3, ch = c & 7;
    *(uint4*)&qs[swz(row, ch)] = cvt8(Q + baseQ + (size_t)row * EMB + ch * 8, qscale);
  }
  // write tile 0, prefetch tile 1
  *(uint4*)&ks[0][kpos0] = kreg0;
  *(uint4*)&ks[0][kpos1] = kreg1;
  *(uint4*)&vs[0][vpos0] = vreg0;
  *(uint4*)&vs[0][vpos1] = vreg1;
  kreg0 = *(const uint4*)(Kb + kvb + (size_t)(128 + r0)      * HD + cc * 8);
  kreg1 = *(const uint4*)(Kb + kvb + (size_t)(192 + r0)      * HD + cc * 8);
  vreg0 = *(const uint4*)(Vt + vtb + (size_t)vr0        * S_LEN + 128 + vch * 8);
  vreg1 = *(const uint4*)(Vt + vtb + (size_t)(vr0 + 32) * S_LEN + 128 + vch * 8);
  __syncthreads();   // qs + buf0 ready

  // Q B-fragments (n = query = ln, k = qd*8+j), loop-invariant
  bf16x8 aq[2];
  #pragma unroll
  for (int kh = 0; kh < 2; ++kh)
    aq[kh] = *(const bf16x8*)&qs[swz(wave * 16 + ln, kh * 4 + qd)];

  // ones B-fragment for lsum-on-MFMA: D[q][*] = sum_k P[q][k]
  bf16x8 ones;
  #pragma unroll
  for (int j = 0; j < 8; ++j) ones[j] = (short)0x3F80;   // bf16 1.0

  f32x4 oacc[4] = {};   // [dn]; C: col=dim=ln, row=query=qd*4+r
  f32x4 lacc = {};      // row sums; C: row=query=qd*4+r (col replicated)

  for (int kt = 0; kt < S_LEN / 128; ++kt) {
    const int cur = kt & 1;
    if (kt + 1 < S_LEN / 128) {     // regs loaded one full iter ago: no stall
      *(uint4*)&ks[1 - cur][kpos0] = kreg0;
      *(uint4*)&ks[1 - cur][kpos1] = kreg1;
      *(uint4*)&vs[1 - cur][vpos0] = vreg0;
      *(uint4*)&vs[1 - cur][vpos1] = vreg1;
      if (kt + 2 < S_LEN / 128) {
        const int kb2 = (kt + 2) * 128;
        kreg0 = *(const uint4*)(Kb + kvb + (size_t)(kb2 + r0)       * HD + cc * 8);
        kreg1 = *(const uint4*)(Kb + kvb + (size_t)(kb2 + 64 + r0)  * HD + cc * 8);
        vreg0 = *(const uint4*)(Vt + vtb + (size_t)vr0        * S_LEN + kb2 + vch * 8);
        vreg1 = *(const uint4*)(Vt + vtb + (size_t)(vr0 + 32) * S_LEN + kb2 + vch * 8);
      }
    }

    // ---- S^T = K Q^T, both 64-key halves back-to-back: 16 independent
    // MFMAs fill the matrix pipe while the trans pipe is still free.
    f32x4 sfA[4], sfB[4];
    __builtin_amdgcn_s_setprio(1);
    #pragma unroll
    for (int k16 = 0; k16 < 4; ++k16) {
      const int krow = k16 * 16 + ln;
      bf16x8 ak0 = *(const bf16x8*)&ks[cur][swz(krow, qd)];
      bf16x8 ak1 = *(const bf16x8*)&ks[cur][swz(krow, 4 + qd)];
      f32x4 acc = {};
      acc = __builtin_amdgcn_mfma_f32_16x16x32_bf16(ak0, aq[0], acc, 0, 0, 0);
      sfA[k16] = __builtin_amdgcn_mfma_f32_16x16x32_bf16(ak1, aq[1], acc, 0, 0, 0);
    }
    #pragma unroll
    for (int k16 = 0; k16 < 4; ++k16) {
      const int krow = (4 + k16) * 16 + ln;
      bf16x8 ak0 = *(const bf16x8*)&ks[cur][swz(krow, qd)];
      bf16x8 ak1 = *(const bf16x8*)&ks[cur][swz(krow, 4 + qd)];
      f32x4 acc = {};
      acc = __builtin_amdgcn_mfma_f32_16x16x32_bf16(ak0, aq[0], acc, 0, 0, 0);
      sfB[k16] = __builtin_amdgcn_mfma_f32_16x16x32_bf16(ak1, aq[1], acc, 0, 0, 0);
    }
    __builtin_amdgcn_s_setprio(0);

    // ---- exp/pack half A -> apA[0..1] (trans pipe; overlaps QK-B tail) ----
    bf16x8 apA[2];
    #pragma unroll
    for (int t2 = 0; t2 < 2; ++t2)
      #pragma unroll
      for (int j = 0; j < 8; ++j) {
        const float p = __builtin_amdgcn_exp2f(sfA[t2 * 2 + (j >> 2)][j & 3]);
        __hip_bfloat16 hb = __float2bfloat16(p);
        apA[t2][j] = *(short*)&hb;
      }

    // ---- PV + lsum for t=0,1 (10 MFMA) — overlaps exp/pack of half B ----
    __builtin_amdgcn_s_setprio(1);
    #pragma unroll
    for (int t = 0; t < 2; ++t) {
      lacc = __builtin_amdgcn_mfma_f32_16x16x32_bf16(apA[t], ones, lacc, 0, 0, 0);
      #pragma unroll
      for (int dn = 0; dn < 4; ++dn) {
        bf16x8 bv = *(const bf16x8*)&vs[cur][swz128(dn * 16 + ln, t * 4 + qd)];
        oacc[dn] = __builtin_amdgcn_mfma_f32_16x16x32_bf16(apA[t], bv, oacc[dn], 0, 0, 0);
      }
    }
    __builtin_amdgcn_s_setprio(0);

    // ---- exp/pack half B -> apB[0..1] ----
    bf16x8 apB[2];
    #pragma unroll
    for (int t2 = 0; t2 < 2; ++t2)
      #pragma unroll
      for (int j = 0; j < 8; ++j) {
        const float p = __builtin_amdgcn_exp2f(sfB[t2 * 2 + (j >> 2)][j & 3]);
        __hip_bfloat16 hb = __float2bfloat16(p);
        apB[t2][j] = *(short*)&hb;
      }

    // ---- PV + lsum for t=2,3 ----
    __builtin_amdgcn_s_setprio(1);
    #pragma unroll
    for (int t = 0; t < 2; ++t) {
      lacc = __builtin_amdgcn_mfma_f32_16x16x32_bf16(apB[t], ones, lacc, 0, 0, 0);
      #pragma unroll
      for (int dn = 0; dn < 4; ++dn) {
        bf16x8 bv = *(const bf16x8*)&vs[cur][swz128(dn * 16 + ln, (2 + t) * 4 + qd)];
        oacc[dn] = __builtin_amdgcn_mfma_f32_16x16x32_bf16(apB[t], bv, oacc[dn], 0, 0, 0);
      }
    }
    __builtin_amdgcn_s_setprio(0);

    __syncthreads();   // single barrier per iteration
  }

  // ---- epilogue: lacc[r] is already this lane's row sums -> normalize ----
  #pragma unroll
  for (int r = 0; r < 4; ++r) {
    const float inv = 1.f / lacc[r];
    const int row = wave * 16 + qd * 4 + r;
    #pragma unroll
    for (int dn = 0; dn < 4; ++dn)
      O[baseQ + (size_t)row * EMB + dn * 16 + ln] =
          __float2bfloat16(oacc[dn][r] * inv);
  }
}

// ---------------------------------------------------------------------------
// Projection (R11/R13-verified, swizzle reverted): Out = PReLU(X @ Wb^T + b).
// 128x64 tile, grid (32,16) = 512 blocks = 2 blocks/CU. 256 thr = 4 waves
// 2x2; 16 MFMA per 12 LDS reads per BK=64 iter. Double-buffered, register
// prefetch, 1 barrier/iter, XOR swizzle, LDS 48 KB.
// ---------------------------------------------------------------------------
__global__ __launch_bounds__(256, 2)
void proj_prelu(const __hip_bfloat16* __restrict__ X,
                const __hip_bfloat16* __restrict__ Wb,
                const float* __restrict__ Bv,
                const float* __restrict__ Pa,
                float* __restrict__ Out)
{
  __shared__ __align__(16) __hip_bfloat16 xs[2][128 * 64];   // 32 KB
  __shared__ __align__(16) __hip_bfloat16 wsm[2][64 * 64];   // 16 KB

  const int m0   = blockIdx.x * 128;
  const int n0   = blockIdx.y * 64;
  const int tid  = threadIdx.x;
  const int wave = tid >> 6;
  const int wm   = wave >> 1;      // 0..1 : 64-row half
  const int wn   = wave & 1;       // 0..1 : 32-col half
  const int lane = tid & 63;
  const int ln   = lane & 15;
  const int qd   = lane >> 4;
  const int r0 = tid >> 3, cc = tid & 7;

  f32x4 acc[8] = {};   // [mf*2+nf]

  uint4 xg0, xg1, xg2, xg3, wg0, wg1;
  #define LOADK(ko)                                                           \
    xg0 = *(const uint4*)(X  + (size_t)(m0 + r0     ) * EMB + (ko) + cc * 8); \
    xg1 = *(const uint4*)(X  + (size_t)(m0 + r0 + 32) * EMB + (ko) + cc * 8); \
    xg2 = *(const uint4*)(X  + (size_t)(m0 + r0 + 64) * EMB + (ko) + cc * 8); \
    xg3 = *(const uint4*)(X  + (size_t)(m0 + r0 + 96) * EMB + (ko) + cc * 8); \
    wg0 = *(const uint4*)(Wb + (size_t)(n0 + r0     ) * EMB + (ko) + cc * 8); \
    wg1 = *(const uint4*)(Wb + (size_t)(n0 + r0 + 32) * EMB + (ko) + cc * 8)
  #define STORELDS(buf)                                                       \
    *(uint4*)&xs [buf][swz(r0,      cc)] = xg0;                               \
    *(uint4*)&xs [buf][swz(r0 + 32, cc)] = xg1;                               \
    *(uint4*)&xs [buf][swz(r0 + 64, cc)] = xg2;                               \
    *(uint4*)&xs [buf][swz(r0 + 96, cc)] = xg3;                               \
    *(uint4*)&wsm[buf][swz(r0,      cc)] = wg0;                               \
    *(uint4*)&wsm[buf][swz(r0 + 32, cc)] = wg1

  LOADK(0);
  STORELDS(0);
  LOADK(64);
  __syncthreads();

  for (int kt = 0; kt < EMB / 64; ++kt) {
    const int cur = kt & 1;
    if (kt + 1 < EMB / 64) {
      STORELDS(1 - cur);
      if (kt + 2 < EMB / 64) {
        LOADK((kt + 2) * 64);
      }
    }

    #pragma unroll
    for (int ks2 = 0; ks2 < 2; ++ks2) {   // two K=32 steps
      bf16x8 ax0 = *(const bf16x8*)&xs[cur][swz(wm * 64 +  0 + ln, ks2 * 4 + qd)];
      bf16x8 ax1 = *(const bf16x8*)&xs[cur][swz(wm * 64 + 16 + ln, ks2 * 4 + qd)];
      bf16x8 ax2 = *(const bf16x8*)&xs[cur][swz(wm * 64 + 32 + ln, ks2 * 4 + qd)];
      bf16x8 ax3 = *(const bf16x8*)&xs[cur][swz(wm * 64 + 48 + ln, ks2 * 4 + qd)];
      bf16x8 bw0 = *(const bf16x8*)&wsm[cur][swz(wn * 32 +  0 + ln, ks2 * 4 + qd)];
      bf16x8 bw1 = *(const bf16x8*)&wsm[cur][swz(wn * 32 + 16 + ln, ks2 * 4 + qd)];
      acc[0] = __builtin_amdgcn_mfma_f32_16x16x32_bf16(ax0, bw0, acc[0], 0, 0, 0);
      acc[1] = __builtin_amdgcn_mfma_f32_16x16x32_bf16(ax0, bw1, acc[1], 0, 0, 0);
      acc[2] = __builtin_amdgcn_mfma_f32_16x16x32_bf16(ax1, bw0, acc[2], 0, 0, 0);
      acc[3] = __builtin_amdgcn_mfma_f32_16x16x32_bf16(ax1, bw1, acc[3], 0, 0, 0);
      acc[4] = __builtin_amdgcn_mfma_f32_16x16x32_bf16(ax2, bw0, acc[4], 0, 0, 0);
      acc[5] = __builtin_amdgcn_mfma_f32_16x16x32_bf16(ax2, bw1, acc[5], 0, 0, 0);
      acc[6] = __builtin_amdgcn_mfma_f32_16x16x32_bf16(ax3, bw0, acc[6], 0, 0, 0);
      acc[7] = __builtin_amdgcn_mfma_f32_16x16x32_bf16(ax3, bw1, acc[7], 0, 0, 0);
    }
    __syncthreads();
  }

  const float a = Pa[0];
  #pragma unroll
  for (int mf = 0; mf < 4; ++mf) {
    #pragma unroll
    for (int nf = 0; nf < 2; ++nf) {
      const float bn = Bv[n0 + wn * 32 + nf * 16 + ln];
      #pragma unroll
      for (int r = 0; r < 4; ++r) {
        float y = acc[mf * 2 + nf][r] + bn;
        y = (y >= 0.f) ? y : a * y;
        Out[(size_t)(m0 + wm * 64 + mf * 16 + qd * 4 + r) * EMB +
            n0 + wn * 32 + nf * 16 + ln] = y;
      }
    }
  }
  #undef LOADK
  #undef STORELDS
}

extern "C" void kernel_launch(void* const* d_in, const int* in_sizes, int n_in,
                              void* d_out, int out_size, void* d_ws, size_t ws_size,
                              hipStream_t stream) {
  const float* Q  = (const float*)d_in[0];
  const float* K  = (const float*)d_in[1];
  const float* V  = (const float*)d_in[2];
  const float* W  = (const float*)d_in[3];
  const float* Bb = (const float*)d_in[4];
  const float* Pa = (const float*)d_in[5];
  float* Out = (float*)d_out;

  // workspace (bytes): X 0..8M, Kb 8..16M, Vt 16..24M, Wb 24..26M
  char* ws = (char*)d_ws;
  __hip_bfloat16* Xws = (__hip_bfloat16*)(ws);
  __hip_bfloat16* Kb  = (__hip_bfloat16*)(ws + (8u  << 20));
  __hip_bfloat16* Vt  = (__hip_bfloat16*)(ws + (16u << 20));
  __hip_bfloat16* Wb  = (__hip_bfloat16*)(ws + (24u << 20));

  prep      <<<dim3(S_LEN / 64, NH, 2), 256, 0, stream>>>(K, V, Kb, Vt);
  attn_fwd  <<<dim3(S_LEN / 128, NH, 3), 512, 0, stream>>>(Q, Kb, Vt, W, Wb, Xws);
  proj_prelu<<<dim3(2 * S_LEN / 128, EMB / 64), 256, 0, stream>>>(Xws, Wb, Bb, Pa, Out);
}